// Round 6
// baseline (144.127 us; speedup 1.0000x reference)
//
#include <hip/hip_runtime.h>

typedef unsigned int u32;
typedef unsigned long long u64;

#define BB 16
#define LL 8192
#define CC 512
#define KK 64
#define CAP 256
#define THRESH 2.1f        // survivors/col: mean~146 sigma~12 -> [64,256] w/ ~7 sigma margin

#define A_COLS 16          // columns per A-block (64B row segment)
#define A_ROWS 2048        // rows per A-block
#define A_THREADS 256      // (cg = tid&3, rt = tid>>2); thread: 4 cols x 32 contiguous rows

// ---- order-preserving fp32 <-> u32 key transforms ----
__device__ __forceinline__ u32 flip_bits(u32 u) {
  return u ^ ((u & 0x80000000u) ? 0xFFFFFFFFu : 0x80000000u);
}
__device__ __forceinline__ u32 unflip_bits(u32 f) {
  return (f & 0x80000000u) ? (f ^ 0x80000000u) : ~f;
}
__device__ __forceinline__ u64 u64max(u64 a, u64 b) { return a > b ? a : b; }
__device__ __forceinline__ u64 u64min(u64 a, u64 b) { return a < b ? a : b; }

// ---------------- Kernel A: streaming bitmask, no cross-lane ops ----------------
// grid = 16b x 32colblk x 4rowblk = 2048 blocks x 256 thr = 32 waves/CU.
// Thread owns 4 cols x 32 contiguous rows -> builds 4 u32 masks in registers.
// 8-deep load batches pinned by sched_barrier(0) -> 8 float4 in flight per wave.
// Masks stored TRANSPOSED: bm[(b*CC + col)*256 + chunk] for coalesced B reads.
__global__ __launch_bounds__(A_THREADS, 8) void kbitmask(const float* __restrict__ x,
                                                         u32* __restrict__ bm) {
  int tid = threadIdx.x;
  int cg = tid & 3;
  int rt = tid >> 2;             // 0..63
  int bid = blockIdx.x;
  int b = bid >> 7;
  int colblk = (bid >> 2) & 31;
  int rowblk = bid & 3;
  int c0 = colblk * A_COLS;
  size_t row0 = (size_t)rowblk * A_ROWS + (size_t)rt * 32;
  const float4* p =
      reinterpret_cast<const float4*>(x + ((size_t)b * LL + row0) * CC + c0) + cg;
  u32 m0 = 0, m1 = 0, m2 = 0, m3 = 0;
  float4 buf[8];
#pragma unroll
  for (int batch = 0; batch < 4; ++batch) {
#pragma unroll
    for (int t = 0; t < 8; ++t) buf[t] = p[(size_t)(batch * 8 + t) * (CC / 4)];
    __builtin_amdgcn_sched_barrier(0);   // loads stay issued before consumers
#pragma unroll
    for (int t = 0; t < 8; ++t) {
      int i = batch * 8 + t;
      m0 |= ((u32)(buf[t].x > THRESH)) << i;
      m1 |= ((u32)(buf[t].y > THRESH)) << i;
      m2 |= ((u32)(buf[t].z > THRESH)) << i;
      m3 |= ((u32)(buf[t].w > THRESH)) << i;
    }
  }
  u32 chunk = (u32)(rowblk * 64 + rt);
  size_t cb = ((size_t)b * CC + c0 + cg * 4) * 256 + chunk;
  bm[cb] = m0;
  bm[cb + 256] = m1;
  bm[cb + 512] = m2;
  bm[cb + 768] = m3;
}

// ---------------- Kernel B: per-column top-64 ----------------
// One wave per column (4/block). Coalesced uint4 mask load (1KB/wave), popc +
// shfl scan, bit-extract + gather values, LDS list, register bitonic-256 ->
// top-64 -> index re-sort -> write. Exact slow path if total outside [64,256].
__global__ __launch_bounds__(256) void kselect(const float* __restrict__ x,
                                               const u32* __restrict__ bm,
                                               float* __restrict__ out,
                                               int force_slow) {
  __shared__ u64 lists[4][CAP];
  int tid = threadIdx.x;
  int lane = tid & 63;
  int w = tid >> 6;
  int ch = blockIdx.x * 4 + w;
  int b = ch >> 9;
  int c = ch & (CC - 1);
  u64* wl = lists[w];
  const float* colp = x + (size_t)b * LL * CC + c;

#pragma unroll
  for (int r = 0; r < 4; ++r) wl[r * 64 + lane] = 0;
  __syncthreads();

  u32 total = 0;
  if (!force_slow) {
    uint4 mv = reinterpret_cast<const uint4*>(bm + (size_t)ch * 256)[lane];
    u32 mk[4] = {mv.x, mv.y, mv.z, mv.w};
    u32 cnt = __popc(mk[0]) + __popc(mk[1]) + __popc(mk[2]) + __popc(mk[3]);
    u32 inc = cnt;
#pragma unroll
    for (int d = 1; d < 64; d <<= 1) {
      u32 o = __shfl_up(inc, d, 64);
      if (lane >= d) inc += o;
    }
    u32 pos = inc - cnt;
    total = __shfl(inc, 63, 64);
#pragma unroll
    for (int j = 0; j < 4; ++j) {
      u32 m = mk[j];
      int base = (lane * 4 + j) * 32;
      while (m) {
        int bit = __builtin_ctz(m);
        m &= m - 1;
        int row = base + bit;
        float v = colp[(size_t)row * CC];
        u64 key = (((u64)flip_bits(__float_as_uint(v))) << 32) | (u32)row;
        if (pos < CAP) wl[pos] = key;
        pos++;
      }
    }
  }
  __syncthreads();

  u64 sel;
  if (!force_slow && total >= (u32)KK && total <= (u32)CAP) {
    u64 kk[4];
#pragma unroll
    for (int r = 0; r < 4; ++r) kk[r] = wl[r * 64 + lane];
    // bitonic sort 256 keys DESCENDING (registers + shfl)
#pragma unroll
    for (int k = 2; k <= 256; k <<= 1) {
#pragma unroll
      for (int j = k >> 1; j > 0; j >>= 1) {
        if (j >= 64) {
          int rj = j >> 6;
#pragma unroll
          for (int r = 0; r < 4; ++r) {
            int pr2 = r ^ rj;
            if (pr2 > r) {
              int e = r * 64 + lane;
              bool descb = ((e & k) == 0);
              u64 a = kk[r], bq = kk[pr2];
              u64 mx = u64max(a, bq), mn = u64min(a, bq);
              kk[r] = descb ? mx : mn;
              kk[pr2] = descb ? mn : mx;
            }
          }
        } else {
#pragma unroll
          for (int r = 0; r < 4; ++r) {
            u64 other = __shfl_xor(kk[r], j, 64);
            int e = r * 64 + lane;
            bool upper = (lane & j) != 0;
            bool descb = ((e & k) == 0);
            bool keepmax = descb ? !upper : upper;
            kk[r] = keepmax ? u64max(kk[r], other) : u64min(kk[r], other);
          }
        }
      }
    }
    sel = kk[0];  // lane i holds i-th largest key
  } else {
    // exact slow path: 64 rounds of wave-reduce max over keys < prev
    u64 prev = ~0ull;
    sel = 0;
    for (int r = 0; r < KK; ++r) {
      u64 local = 0;
      for (int t = 0; t < LL / 64; ++t) {
        int l = t * 64 + lane;
        float vv = colp[(size_t)l * CC];
        u64 key = (((u64)flip_bits(__float_as_uint(vv))) << 32) | (u32)l;
        if (key < prev) local = u64max(local, key);
      }
#pragma unroll
      for (int m = 32; m > 0; m >>= 1) local = u64max(local, __shfl_xor(local, m, 64));
      if (lane == r) sel = local;
      prev = local;
    }
  }

  // re-key by (index, value), sort ASCENDING -> original sequence order
  u32 f = (u32)(sel >> 32);
  u32 l = (u32)sel;
  u64 s2 = (((u64)l) << 32) | f;
#pragma unroll
  for (int k = 2; k <= 64; k <<= 1) {
#pragma unroll
    for (int j = k >> 1; j > 0; j >>= 1) {
      u64 other = __shfl_xor(s2, j, 64);
      bool upper = (lane & j) != 0;
      bool ascb = ((lane & k) == 0);
      bool keepmax = ascb ? upper : !upper;
      s2 = keepmax ? u64max(s2, other) : u64min(s2, other);
    }
  }
  out[((size_t)b * KK + lane) * CC + c] = __uint_as_float(unflip_bits((u32)s2));
}

extern "C" void kernel_launch(void* const* d_in, const int* in_sizes, int n_in,
                              void* d_out, int out_size, void* d_ws, size_t ws_size,
                              hipStream_t stream) {
  const float* x = (const float*)d_in[0];
  float* out = (float*)d_out;
  const size_t need = (size_t)BB * CC * 256 * sizeof(u32);  // 8 MB transposed bitmasks
  if (d_ws != nullptr && ws_size >= need) {
    u32* bm = (u32*)d_ws;
    kbitmask<<<BB * 32 * 4, A_THREADS, 0, stream>>>(x, bm);
    kselect<<<(BB * CC) / 4, 256, 0, stream>>>(x, bm, out, 0);
  } else {
    kselect<<<(BB * CC) / 4, 256, 0, stream>>>(x, nullptr, out, 1);
  }
}

// Round 7
// 143.366 us; speedup vs baseline: 1.0053x; 1.0053x over previous
//
#include <hip/hip_runtime.h>

typedef unsigned int u32;
typedef unsigned long long u64;

#define BB 16
#define LL 8192
#define CC 512
#define KK 64
#define CAP 256
#define THRESH 2.1f        // survivors/col: mean~146 sigma~12 -> [64,256] w/ ~7 sigma margin

#define A_THREADS 256      // thread: 4 cols x 32 contiguous rows

// ---- order-preserving fp32 <-> u32 key transforms ----
__device__ __forceinline__ u32 flip_bits(u32 u) {
  return u ^ ((u & 0x80000000u) ? 0xFFFFFFFFu : 0x80000000u);
}
__device__ __forceinline__ u32 unflip_bits(u32 f) {
  return (f & 0x80000000u) ? (f ^ 0x80000000u) : ~f;
}
__device__ __forceinline__ u64 u64max(u64 a, u64 b) { return a > b ? a : b; }
__device__ __forceinline__ u64 u64min(u64 a, u64 b) { return a < b ? a : b; }

// ---------------- Kernel A: pure streaming bitmask ----------------
// grid = 16b x 32colblk x 4rowblk = 2048 blocks x 256 thr = 32 waves/CU.
// Thread owns 4 cols x 32 contiguous rows; plain unrolled compare/OR loop —
// no cross-lane ops, no sched_barrier (R6 lesson: it drains the pipeline).
// Mask tile transposed through padded LDS so the global write is uint4-
// coalesced in the [col][chunk] layout kernel B reads.
__global__ __launch_bounds__(A_THREADS) void kbitmask(const float* __restrict__ x,
                                                      u32* __restrict__ bm) {
  __shared__ u32 T[16][65];      // [col][chunk-in-block], padded
  int tid = threadIdx.x;
  int cg = tid & 3;
  int rt = tid >> 2;             // 0..63 chunk-in-block
  int bid = blockIdx.x;
  int b = bid >> 7;
  int colblk = (bid >> 2) & 31;
  int rowblk = bid & 3;
  int c0 = colblk * 16;
  size_t row0 = (size_t)rowblk * 2048 + (size_t)rt * 32;
  const float4* p =
      reinterpret_cast<const float4*>(x + ((size_t)b * LL + row0) * CC + c0) + cg;
  u32 m0 = 0, m1 = 0, m2 = 0, m3 = 0;
#pragma unroll 8
  for (int i = 0; i < 32; ++i) {
    float4 v = p[(size_t)i * (CC / 4)];
    m0 |= ((u32)(v.x > THRESH)) << i;
    m1 |= ((u32)(v.y > THRESH)) << i;
    m2 |= ((u32)(v.z > THRESH)) << i;
    m3 |= ((u32)(v.w > THRESH)) << i;
  }
  T[cg * 4 + 0][rt] = m0;
  T[cg * 4 + 1][rt] = m1;
  T[cg * 4 + 2][rt] = m2;
  T[cg * 4 + 3][rt] = m3;
  __syncthreads();
  int col = tid >> 4;
  int grp = tid & 15;
  uint4 o = make_uint4(T[col][grp * 4 + 0], T[col][grp * 4 + 1],
                       T[col][grp * 4 + 2], T[col][grp * 4 + 3]);
  reinterpret_cast<uint4*>(bm + ((size_t)b * CC + c0 + col) * 256 + rowblk * 64)[grp] = o;
}

// ---------------- Kernel B: per-column top-64 (validated in R6) ----------------
// One wave per column (4/block). Coalesced uint4 mask load (1KB/wave), popc +
// shfl scan, bit-extract + gather values, LDS list, register bitonic-256 ->
// top-64 -> index re-sort -> write. Exact slow path if total outside [64,256].
__global__ __launch_bounds__(256) void kselect(const float* __restrict__ x,
                                               const u32* __restrict__ bm,
                                               float* __restrict__ out,
                                               int force_slow) {
  __shared__ u64 lists[4][CAP];
  int tid = threadIdx.x;
  int lane = tid & 63;
  int w = tid >> 6;
  int ch = blockIdx.x * 4 + w;
  int b = ch >> 9;
  int c = ch & (CC - 1);
  u64* wl = lists[w];
  const float* colp = x + (size_t)b * LL * CC + c;

#pragma unroll
  for (int r = 0; r < 4; ++r) wl[r * 64 + lane] = 0;
  __syncthreads();

  u32 total = 0;
  if (!force_slow) {
    uint4 mv = reinterpret_cast<const uint4*>(bm + (size_t)ch * 256)[lane];
    u32 mk[4] = {mv.x, mv.y, mv.z, mv.w};
    u32 cnt = __popc(mk[0]) + __popc(mk[1]) + __popc(mk[2]) + __popc(mk[3]);
    u32 inc = cnt;
#pragma unroll
    for (int d = 1; d < 64; d <<= 1) {
      u32 o = __shfl_up(inc, d, 64);
      if (lane >= d) inc += o;
    }
    u32 pos = inc - cnt;
    total = __shfl(inc, 63, 64);
#pragma unroll
    for (int j = 0; j < 4; ++j) {
      u32 m = mk[j];
      int base = (lane * 4 + j) * 32;
      while (m) {
        int bit = __builtin_ctz(m);
        m &= m - 1;
        int row = base + bit;
        float v = colp[(size_t)row * CC];
        u64 key = (((u64)flip_bits(__float_as_uint(v))) << 32) | (u32)row;
        if (pos < CAP) wl[pos] = key;
        pos++;
      }
    }
  }
  __syncthreads();

  u64 sel;
  if (!force_slow && total >= (u32)KK && total <= (u32)CAP) {
    u64 kk[4];
#pragma unroll
    for (int r = 0; r < 4; ++r) kk[r] = wl[r * 64 + lane];
    // bitonic sort 256 keys DESCENDING (registers + shfl)
#pragma unroll
    for (int k = 2; k <= 256; k <<= 1) {
#pragma unroll
      for (int j = k >> 1; j > 0; j >>= 1) {
        if (j >= 64) {
          int rj = j >> 6;
#pragma unroll
          for (int r = 0; r < 4; ++r) {
            int pr2 = r ^ rj;
            if (pr2 > r) {
              int e = r * 64 + lane;
              bool descb = ((e & k) == 0);
              u64 a = kk[r], bq = kk[pr2];
              u64 mx = u64max(a, bq), mn = u64min(a, bq);
              kk[r] = descb ? mx : mn;
              kk[pr2] = descb ? mn : mx;
            }
          }
        } else {
#pragma unroll
          for (int r = 0; r < 4; ++r) {
            u64 other = __shfl_xor(kk[r], j, 64);
            int e = r * 64 + lane;
            bool upper = (lane & j) != 0;
            bool descb = ((e & k) == 0);
            bool keepmax = descb ? !upper : upper;
            kk[r] = keepmax ? u64max(kk[r], other) : u64min(kk[r], other);
          }
        }
      }
    }
    sel = kk[0];  // lane i holds i-th largest key
  } else {
    // exact slow path: 64 rounds of wave-reduce max over keys < prev
    u64 prev = ~0ull;
    sel = 0;
    for (int r = 0; r < KK; ++r) {
      u64 local = 0;
      for (int t = 0; t < LL / 64; ++t) {
        int l = t * 64 + lane;
        float vv = colp[(size_t)l * CC];
        u64 key = (((u64)flip_bits(__float_as_uint(vv))) << 32) | (u32)l;
        if (key < prev) local = u64max(local, key);
      }
#pragma unroll
      for (int m = 32; m > 0; m >>= 1) local = u64max(local, __shfl_xor(local, m, 64));
      if (lane == r) sel = local;
      prev = local;
    }
  }

  // re-key by (index, value), sort ASCENDING -> original sequence order
  u32 f = (u32)(sel >> 32);
  u32 l = (u32)sel;
  u64 s2 = (((u64)l) << 32) | f;
#pragma unroll
  for (int k = 2; k <= 64; k <<= 1) {
#pragma unroll
    for (int j = k >> 1; j > 0; j >>= 1) {
      u64 other = __shfl_xor(s2, j, 64);
      bool upper = (lane & j) != 0;
      bool ascb = ((lane & k) == 0);
      bool keepmax = ascb ? upper : !upper;
      s2 = keepmax ? u64max(s2, other) : u64min(s2, other);
    }
  }
  out[((size_t)b * KK + lane) * CC + c] = __uint_as_float(unflip_bits((u32)s2));
}

extern "C" void kernel_launch(void* const* d_in, const int* in_sizes, int n_in,
                              void* d_out, int out_size, void* d_ws, size_t ws_size,
                              hipStream_t stream) {
  const float* x = (const float*)d_in[0];
  float* out = (float*)d_out;
  const size_t need = (size_t)BB * CC * 256 * sizeof(u32);  // 8 MB transposed bitmasks
  if (d_ws != nullptr && ws_size >= need) {
    u32* bm = (u32*)d_ws;
    kbitmask<<<BB * 32 * 4, A_THREADS, 0, stream>>>(x, bm);
    kselect<<<(BB * CC) / 4, 256, 0, stream>>>(x, bm, out, 0);
  } else {
    kselect<<<(BB * CC) / 4, 256, 0, stream>>>(x, nullptr, out, 1);
  }
}

// Round 8
// 109.960 us; speedup vs baseline: 1.3107x; 1.3038x over previous
//
#include <hip/hip_runtime.h>

typedef unsigned int u32;
typedef unsigned long long u64;

#define BB 16
#define LL 8192
#define CC 512
#define KK 64
#define LCH 256          // L-chunks per batch
#define LPB 32           // rows per chunk (bitmask width)
#define CAP 256
#define THRESH 2.1f      // survivors/col: mean~146 sigma~12 -> [64,256] w/ ~7 sigma margin

// ---- order-preserving fp32 <-> u32 key transforms ----
__device__ __forceinline__ u32 flip_bits(u32 u) {
  return u ^ ((u & 0x80000000u) ? 0xFFFFFFFFu : 0x80000000u);
}
__device__ __forceinline__ u32 unflip_bits(u32 f) {
  return (f & 0x80000000u) ? (f ^ 0x80000000u) : ~f;
}
__device__ __forceinline__ u64 u64max(u64 a, u64 b) { return a > b ? a : b; }
__device__ __forceinline__ u64 u64min(u64 a, u64 b) { return a < b ? a : b; }

// ---------------- Kernel A (R2-proven): full-row streaming bitmask ----------------
// grid = BB*LCH = 4096 blocks x 128 threads. Block = 32 rows x ALL 512 cols;
// per wave-iteration the block reads one full contiguous 2KB row -> max DRAM
// page locality (the stripe geometries of R4/R6/R7 were 40us slower).
// No cross-lane ops, no atomics. Masks stored [chunk][col], uint4 per thread.
__global__ __launch_bounds__(128) void kbitmask(const float* __restrict__ x,
                                                u32* __restrict__ bm) {
  int blk = blockIdx.x;
  int b = blk >> 8;
  int chunk = blk & (LCH - 1);
  int t = threadIdx.x;
  const float4* p =
      reinterpret_cast<const float4*>(x + ((size_t)b * LL + (size_t)chunk * LPB) * CC) + t;
  u32 m0 = 0, m1 = 0, m2 = 0, m3 = 0;
#pragma unroll
  for (int i = 0; i < LPB; ++i) {
    float4 v = p[(size_t)i * (CC / 4)];
    m0 |= ((u32)(v.x > THRESH)) << i;
    m1 |= ((u32)(v.y > THRESH)) << i;
    m2 |= ((u32)(v.z > THRESH)) << i;
    m3 |= ((u32)(v.w > THRESH)) << i;
  }
  uint4* dst = reinterpret_cast<uint4*>(bm + (size_t)(b * LCH + chunk) * CC) + t;
  *dst = make_uint4(m0, m1, m2, m3);
}

// ---------------- Kernel B: 16-col blocks, L1-reused masks + local gather ----------------
// Block = 256 thr (4 waves) owns 16 consecutive cols; cc-loop processes cols
// c0 + cc*4 + w, so the 4 waves always work on 4 ADJACENT cols (gather-line
// sharing). Mask footprint/block = 16KB -> L1-resident after first col. Select
// = validated popc/scan + gather + register bitonic-256 -> top-64 -> index
// re-sort. Exact slow-path backstop per column.
__global__ __launch_bounds__(256) void kselect(const float* __restrict__ x,
                                               const u32* __restrict__ bm,
                                               float* __restrict__ out,
                                               int force_slow) {
  __shared__ u64 lists[4][CAP];
  int tid = threadIdx.x;
  int lane = tid & 63;
  int w = tid >> 6;
  int grp = blockIdx.x;           // 512 groups of 16 columns
  int b = grp >> 5;
  int c0 = (grp & 31) * 16;
  u64* wl = lists[w];

  for (int cc = 0; cc < 4; ++cc) {
    int c = c0 + cc * 4 + w;
    const float* colp = x + (size_t)b * LL * CC + c;
#pragma unroll
    for (int r = 0; r < 4; ++r) wl[r * 64 + lane] = 0;
    __syncthreads();

    u32 total = 0;
    if (!force_slow) {
      u32 mk[4];
#pragma unroll
      for (int j = 0; j < 4; ++j)
        mk[j] = bm[((size_t)b * LCH + (u32)(lane * 4 + j)) * CC + c];
      u32 cnt = __popc(mk[0]) + __popc(mk[1]) + __popc(mk[2]) + __popc(mk[3]);
      u32 inc = cnt;
#pragma unroll
      for (int d = 1; d < 64; d <<= 1) {
        u32 o = __shfl_up(inc, d, 64);
        if (lane >= d) inc += o;
      }
      u32 pos = inc - cnt;
      total = __shfl(inc, 63, 64);
#pragma unroll
      for (int j = 0; j < 4; ++j) {
        u32 m = mk[j];
        int base = (lane * 4 + j) * LPB;
        while (m) {
          int bit = __builtin_ctz(m);
          m &= m - 1;
          int row = base + bit;
          float v = colp[(size_t)row * CC];
          u64 key = (((u64)flip_bits(__float_as_uint(v))) << 32) | (u32)row;
          if (pos < CAP) wl[pos] = key;
          pos++;
        }
      }
    }
    __syncthreads();

    u64 sel;
    if (!force_slow && total >= (u32)KK && total <= (u32)CAP) {
      u64 kk[4];
#pragma unroll
      for (int r = 0; r < 4; ++r) kk[r] = wl[r * 64 + lane];
      // bitonic sort 256 keys DESCENDING (registers + shfl)
#pragma unroll
      for (int k = 2; k <= 256; k <<= 1) {
#pragma unroll
        for (int j = k >> 1; j > 0; j >>= 1) {
          if (j >= 64) {
            int rj = j >> 6;
#pragma unroll
            for (int r = 0; r < 4; ++r) {
              int pr2 = r ^ rj;
              if (pr2 > r) {
                int e = r * 64 + lane;
                bool descb = ((e & k) == 0);
                u64 a = kk[r], bq = kk[pr2];
                u64 mx = u64max(a, bq), mn = u64min(a, bq);
                kk[r] = descb ? mx : mn;
                kk[pr2] = descb ? mn : mx;
              }
            }
          } else {
#pragma unroll
            for (int r = 0; r < 4; ++r) {
              u64 other = __shfl_xor(kk[r], j, 64);
              int e = r * 64 + lane;
              bool upper = (lane & j) != 0;
              bool descb = ((e & k) == 0);
              bool keepmax = descb ? !upper : upper;
              kk[r] = keepmax ? u64max(kk[r], other) : u64min(kk[r], other);
            }
          }
        }
      }
      sel = kk[0];  // lane i holds i-th largest key
    } else {
      // exact slow path: 64 rounds of wave-reduce max over keys < prev
      u64 prev = ~0ull;
      sel = 0;
      for (int r = 0; r < KK; ++r) {
        u64 local = 0;
        for (int t = 0; t < LL / 64; ++t) {
          int l = t * 64 + lane;
          float vv = colp[(size_t)l * CC];
          u64 key = (((u64)flip_bits(__float_as_uint(vv))) << 32) | (u32)l;
          if (key < prev) local = u64max(local, key);
        }
#pragma unroll
        for (int m = 32; m > 0; m >>= 1) local = u64max(local, __shfl_xor(local, m, 64));
        if (lane == r) sel = local;
        prev = local;
      }
    }

    // re-key by (index, value), sort ASCENDING -> original sequence order
    u32 f = (u32)(sel >> 32);
    u32 l = (u32)sel;
    u64 s2 = (((u64)l) << 32) | f;
#pragma unroll
    for (int k = 2; k <= 64; k <<= 1) {
#pragma unroll
      for (int j = k >> 1; j > 0; j >>= 1) {
        u64 other = __shfl_xor(s2, j, 64);
        bool upper = (lane & j) != 0;
        bool ascb = ((lane & k) == 0);
        bool keepmax = ascb ? upper : !upper;
        s2 = keepmax ? u64max(s2, other) : u64min(s2, other);
      }
    }
    out[((size_t)b * KK + lane) * CC + c] = __uint_as_float(unflip_bits((u32)s2));
    __syncthreads();  // lists reused next cc
  }
}

extern "C" void kernel_launch(void* const* d_in, const int* in_sizes, int n_in,
                              void* d_out, int out_size, void* d_ws, size_t ws_size,
                              hipStream_t stream) {
  const float* x = (const float*)d_in[0];
  float* out = (float*)d_out;
  const size_t need = (size_t)BB * LCH * CC * sizeof(u32);  // 8 MB of bitmasks
  if (d_ws != nullptr && ws_size >= need) {
    u32* bm = (u32*)d_ws;
    kbitmask<<<BB * LCH, 128, 0, stream>>>(x, bm);
    kselect<<<512, 256, 0, stream>>>(x, bm, out, 0);
  } else {
    kselect<<<512, 256, 0, stream>>>(x, nullptr, out, 1);
  }
}